// Round 12
// baseline (234.187 us; speedup 1.0000x reference)
//
#include <hip/hip_runtime.h>

typedef unsigned short u16;
typedef unsigned int u32;
typedef __bf16 bf16x8 __attribute__((ext_vector_type(8)));
typedef float floatx4 __attribute__((ext_vector_type(4)));

#define BB 2
#define TT 2048
#define DD 1024
#define HH 16
#define DKK 64
#define ACT (BB * TT * DD)      // 4194304 elements
#define WTE (DD * DD)           // 1048576 elements

__device__ inline u16 f2bf(float f) {
    union { float f; u32 u; } c; c.f = f;
    u32 r = (c.u + 0x7fffu + ((c.u >> 16) & 1u)) >> 16;
    return (u16)r;
}
__device__ inline u32 pack2bf(float a, float b) {
    return (u32)f2bf(a) | ((u32)f2bf(b) << 16);
}

// async global->LDS, 16B per lane; LDS dest = wave-uniform base + lane*16
typedef __attribute__((address_space(1))) const u32 gas_u32;
typedef __attribute__((address_space(3))) u32 las_u32;
__device__ __forceinline__ void gl2lds16(const u16* g, u16* l) {
    __builtin_amdgcn_global_load_lds((gas_u32*)g, (las_u32*)l, 16, 0, 0);
}

// pack 2 f32 -> 1 u32 of 2 bf16 (RNE, bit-identical to f2bf), 1 VALU op
__device__ __forceinline__ u32 cvtpk_bf16(float lo, float hi) {
    u32 r;
    asm("v_cvt_pk_bf16_f32 %0, %1, %2" : "=v"(r) : "v"(lo), "v"(hi));
    return r;
}

// swap32 then swap16 between two VGPRs (quad = 16-lane group):
//   after: a = {a.q0, a.q2, b.q0, b.q2}, b = {a.q1, a.q3, b.q1, b.q3}
__device__ __forceinline__ void quad_gather(u32 &a, u32 &b) {
    asm volatile("s_nop 1\n\t"
                 "v_permlane32_swap_b32 %0, %1\n\t"
                 "s_nop 1\n\t"
                 "v_permlane16_swap_b32 %0, %1"
                 : "+v"(a), "+v"(b));
}

// ---------------- fp32 -> bf16 convert pass ----------------
// t=0..2: activations (256 blocks x 16384 floats); t=3..6: weights (64 blocks)
// (In-flight conversion inside qkv_gemm was tried R9/R10: latency-bound,
// 86-93us vs 56us here. gl2lds from pre-converted bf16 wins.)
struct CvtArgs { const float* src[7]; u16* dst[7]; };
__global__ __launch_bounds__(256) void convert_bf16(CvtArgs a) {
    int bid = blockIdx.x, t, local;
    if (bid < 768) { t = bid >> 8; local = bid & 255; }
    else { int r = bid - 768; t = 3 + (r >> 6); local = r & 63; }
    const float* s = a.src[t];
    u16* d = a.dst[t];
    const int base = local * 16384;
    for (int i = 0; i < 8; i++) {
        const int idx = base + i * 2048 + threadIdx.x * 8;
        float4 x0 = *(const float4*)(s + idx);
        float4 x1 = *(const float4*)(s + idx + 4);
        uint4 p;
        p.x = pack2bf(x0.x, x0.y); p.y = pack2bf(x0.z, x0.w);
        p.z = pack2bf(x1.x, x1.y); p.w = pack2bf(x1.z, x1.w);
        *(uint4*)(d + idx) = p;
    }
}

// ---------------- fused QKV projection (R8 structure, measured-good) ------
// all-bf16 A[4096,1024] x W[1024,1024]^T; 128x32 LDS tiles via gl2lds w=16.
// grid = 768 1-D, XCD-bijective swizzle (8 x 96): A-panels fetched once per
// XCD, 2MB W slice L2-resident. z=0:Q z=1:K -> ws[b][h][t][dk];
// z=2:V -> [b][h][dk][t] with 8B packed uint2 stores.
__global__ __launch_bounds__(256) void qkv_gemm(
    const u16* __restrict__ Qc, const u16* __restrict__ Kc,
    const u16* __restrict__ Vc,
    const u16* __restrict__ Wqc, const u16* __restrict__ Wkc,
    const u16* __restrict__ Wvc,
    const float* __restrict__ bq, const float* __restrict__ bk,
    const float* __restrict__ bv,
    u16* __restrict__ ws)
{
    __shared__ __align__(16) u16 As[128 * 32];
    __shared__ __align__(16) u16 Bs[128 * 32];
    const int l = (blockIdx.x & 7) * 96 + (blockIdx.x >> 3);
    const int z = l >> 8;              // 256 logical blocks per slice
    const int yy = (l & 255) >> 3;     // m-panel
    const int xx = l & 7;              // n-panel
    const u16* A = (z == 0) ? Qc : (z == 1) ? Kc : Vc;
    const u16* W = (z == 0) ? Wqc : (z == 1) ? Wkc : Wvc;
    const float* bias = (z == 0) ? bq : (z == 1) ? bk : bv;
    u16* out = ws + (size_t)z * (size_t)BB * HH * TT * DKK;

    const int tid  = threadIdx.x;
    const int wave = tid >> 6, lane = tid & 63;
    const int quad = lane >> 4, l16 = lane & 15;
    const int wm = wave & 1, wn = wave >> 1;
    const int m0 = yy * 128, n0 = xx * 128;
    const int K = DD;

    const int lrow = lane >> 2, lcol = (lane & 3) * 8;
    const u16* Ag0 = A + (size_t)(m0 + wave * 16 + lrow) * K + lcol;
    const u16* Ag1 = A + (size_t)(m0 + 64 + wave * 16 + lrow) * K + lcol;
    const u16* Wg0 = W + (size_t)(n0 + wave * 16 + lrow) * K + lcol;
    const u16* Wg1 = W + (size_t)(n0 + 64 + wave * 16 + lrow) * K + lcol;
    u16* AsD0 = &As[(wave * 16) * 32];
    u16* AsD1 = &As[(64 + wave * 16) * 32];
    u16* BsD0 = &Bs[(wave * 16) * 32];
    u16* BsD1 = &Bs[(64 + wave * 16) * 32];

    floatx4 acc[4][4];
    for (int i = 0; i < 4; i++)
        for (int j = 0; j < 4; j++)
            acc[i][j] = floatx4{0.f, 0.f, 0.f, 0.f};

    for (int k0 = 0; k0 < K; k0 += 32) {
        __syncthreads();
        gl2lds16(Ag0 + k0, AsD0);
        gl2lds16(Ag1 + k0, AsD1);
        gl2lds16(Wg0 + k0, BsD0);
        gl2lds16(Wg1 + k0, BsD1);
        __syncthreads();   // compiler emits vmcnt(0) drain before barrier

        bf16x8 af[4], bfr[4];
        for (int mi = 0; mi < 4; mi++)
            af[mi] = *(const bf16x8*)&As[(wm * 64 + mi * 16 + l16) * 32 + quad * 8];
        for (int ni = 0; ni < 4; ni++)
            bfr[ni] = *(const bf16x8*)&Bs[(wn * 64 + ni * 16 + l16) * 32 + quad * 8];
        for (int mi = 0; mi < 4; mi++)
            for (int ni = 0; ni < 4; ni++)
                acc[mi][ni] = __builtin_amdgcn_mfma_f32_16x16x32_bf16(
                    af[mi], bfr[ni], acc[mi][ni], 0, 0, 0);
    }

    for (int ni = 0; ni < 4; ni++) {
        const int n = n0 + wn * 64 + ni * 16 + l16;
        const float bv2 = bias[n];
        const int h = n >> 6, dk = n & 63;
        for (int mi = 0; mi < 4; mi++) {
            if (z == 2) {
                // 4 consecutive t -> one aligned 8B store into V^T
                const int m = m0 + wm * 64 + mi * 16 + quad * 4;
                const int b = m >> 11, t = m & 2047;
                uint2 pp;
                pp.x = pack2bf(acc[mi][ni][0] + bv2, acc[mi][ni][1] + bv2);
                pp.y = pack2bf(acc[mi][ni][2] + bv2, acc[mi][ni][3] + bv2);
                *(uint2*)&out[(((size_t)(b * HH + h)) * DKK + dk) * TT + t] = pp;
            } else {
                for (int vv = 0; vv < 4; vv++) {
                    const int m = m0 + wm * 64 + mi * 16 + quad * 4 + vv;
                    const int b = m >> 11, t = m & 2047;
                    out[(((size_t)(b * HH + h)) * TT + t) * DKK + dk] =
                        f2bf(acc[mi][ni][vv] + bv2);
                }
            }
        }
    }
}

// ---------------- output projection: 64x128 tiles ----------------
// grid = 512 (2 blocks/CU, 8 waves/CU), XCD-bijective swizzle (512 = 8 x 64).
__global__ __launch_bounds__(256) void out_gemm(
    const u16* __restrict__ Av, const u16* __restrict__ Wv,
    const float* __restrict__ bias, float* __restrict__ outv)
{
    __shared__ __align__(16) u16 As[64 * 32];
    __shared__ __align__(16) u16 Bs[128 * 32];
    const int l = (blockIdx.x & 7) * 64 + (blockIdx.x >> 3);
    const int yy = l >> 3, xx = l & 7;
    const int tid  = threadIdx.x;
    const int wave = tid >> 6, lane = tid & 63;
    const int quad = lane >> 4, l16 = lane & 15;
    const int wm = wave & 1, wn = wave >> 1;
    const int m0 = yy * 64, n0 = xx * 128;
    const int K = DD, N = DD;

    const int lrow = lane >> 2, lcol = (lane & 3) * 8;
    const u16* Ag0 = Av + (size_t)(m0 + wave * 16 + lrow) * K + lcol;  // 64 rows
    const u16* Wg0 = Wv + (size_t)(n0 + wave * 16 + lrow) * K + lcol;
    const u16* Wg1 = Wv + (size_t)(n0 + 64 + wave * 16 + lrow) * K + lcol;
    u16* AsD0 = &As[(wave * 16) * 32];
    u16* BsD0 = &Bs[(wave * 16) * 32];
    u16* BsD1 = &Bs[(64 + wave * 16) * 32];

    floatx4 acc[2][4];
    for (int i = 0; i < 2; i++)
        for (int j = 0; j < 4; j++)
            acc[i][j] = floatx4{0.f, 0.f, 0.f, 0.f};

    for (int k0 = 0; k0 < K; k0 += 32) {
        __syncthreads();
        gl2lds16(Ag0 + k0, AsD0);
        gl2lds16(Wg0 + k0, BsD0);
        gl2lds16(Wg1 + k0, BsD1);
        __syncthreads();

        bf16x8 af[2], bfr[4];
        for (int mi = 0; mi < 2; mi++)
            af[mi] = *(const bf16x8*)&As[(wm * 32 + mi * 16 + l16) * 32 + quad * 8];
        for (int ni = 0; ni < 4; ni++)
            bfr[ni] = *(const bf16x8*)&Bs[(wn * 64 + ni * 16 + l16) * 32 + quad * 8];
        for (int mi = 0; mi < 2; mi++)
            for (int ni = 0; ni < 4; ni++)
                acc[mi][ni] = __builtin_amdgcn_mfma_f32_16x16x32_bf16(
                    af[mi], bfr[ni], acc[mi][ni], 0, 0, 0);
    }

    for (int ni = 0; ni < 4; ni++) {
        const int n = n0 + wn * 64 + ni * 16 + l16;
        const float bv2 = bias[n];
        for (int mi = 0; mi < 2; mi++)
            for (int vv = 0; vv < 4; vv++) {
                const int m = m0 + wm * 32 + mi * 16 + quad * 4 + vv;
                outv[(size_t)m * N + n] = acc[mi][ni][vv] + bv2;
            }
    }
}

// ---------------- flash attention: 8 waves x 16 q-rows, swizzled LDS ------
// 16 waves/CU, reg-staged K/V, zero-conflict XOR LDS swizzle, in-register P.
// NEW (T1): XCD-bijective block swizzle -- logical l = (bid&7)*64 + (bid>>3)
// gives each XCD 64 consecutive logical blocks = 4 bh-groups x all 16 qt, so
// each (b,h)'s 512KB K/V stream is fetched by exactly ONE XCD and stays
// L2-resident. R11 FETCH was 69.7MB vs ~25MB ideal (16 qt blocks of one bh
// scattered over all 8 XCDs = 8x K/V re-fetch).
__global__ __launch_bounds__(512) void attn_kernel(
    const u16* __restrict__ Qp, const u16* __restrict__ Kp,
    const u16* __restrict__ Vpt, const int* __restrict__ mask,
    u16* __restrict__ Xa)
{
    __shared__ __align__(16) u16 Ks[64 * 64];     // [key][dk] swizzled
    __shared__ __align__(16) u16 Vs[64 * 64];     // [dk][key] swizzled
    const int tid  = threadIdx.x;
    const int wave = tid >> 6, lane = tid & 63;
    const int quad = lane >> 4, l16 = lane & 15;
    const int bid = blockIdx.x;
    const int lg = (bid & 7) * 64 + (bid >> 3);   // XCD-bijective (512 = 8x64)
    const int qt = lg & 15, bh = lg >> 4;
    const int b = bh >> 4, h = bh & 15;
    const int qbase = qt * 128 + wave * 16;

    const u16* Qb = Qp + (size_t)bh * TT * DKK;
    const u16* Kb = Kp + (size_t)bh * TT * DKK;
    const u16* Vb = Vpt + (size_t)bh * DKK * TT;
    const int* mk = mask + b * TT;

    const int srow = tid >> 3, sg = tid & 7;
    const int sgs = sg ^ (srow & 7);
    const u16* Ksrc = Kb + (size_t)srow * DKK + sgs * 8;
    const u16* Vsrc = Vb + (size_t)srow * TT + sgs * 8;
    u16* KsD = &Ks[srow * 64 + sg * 8];
    u16* VsD = &Vs[srow * 64 + sg * 8];

    const int x7 = l16 & 7;
    const int rg0 = (quad ^ x7) * 8;
    const int rg1 = ((quad + 4) ^ x7) * 8;

    const bf16x8 qf0 = *(const bf16x8*)&Qb[(size_t)(qbase + l16) * DKK + quad * 8];
    const bf16x8 qf1 = *(const bf16x8*)&Qb[(size_t)(qbase + l16) * DKK + 32 + quad * 8];

    floatx4 o[4];
    for (int i = 0; i < 4; i++) o[i] = floatx4{0.f, 0.f, 0.f, 0.f};
    float rs = 0.f;

    uint4 kr = *(const uint4*)Ksrc;
    uint4 vr = *(const uint4*)Vsrc;

    for (int ti = 0; ti < TT / 64; ti++) {
        const int k0 = ti * 64;
        __syncthreads();
        *(uint4*)KsD = kr;
        *(uint4*)VsD = vr;
        __syncthreads();
        if (ti + 1 < TT / 64) {
            kr = *(const uint4*)(Ksrc + (size_t)(k0 + 64) * DKK);
            vr = *(const uint4*)(Vsrc + (k0 + 64));
        }

        const int mv0 = mk[k0 + l16];
        const int mv1 = mk[k0 + 16 + l16];
        const int mv2 = mk[k0 + 32 + l16];
        const int mv3 = mk[k0 + 48 + l16];
        if (!__any(mv0 | mv1 | mv2 | mv3)) continue;
        const bool allv = __all(mv0 && mv1 && mv2 && mv3);

        bf16x8 kf[4][2];
        #pragma unroll
        for (int c = 0; c < 4; c++) {
            const u16* kb = &Ks[(c * 16 + l16) * 64];
            kf[c][0] = *(const bf16x8*)&kb[rg0];
            kf[c][1] = *(const bf16x8*)&kb[rg1];
        }

        floatx4 s[4];
        #pragma unroll
        for (int c = 0; c < 4; c++) s[c] = floatx4{0.f, 0.f, 0.f, 0.f};
        #pragma unroll
        for (int c = 0; c < 4; c++) {
            s[c] = __builtin_amdgcn_mfma_f32_16x16x32_bf16(kf[c][0], qf0, s[c], 0, 0, 0);
            s[c] = __builtin_amdgcn_mfma_f32_16x16x32_bf16(kf[c][1], qf1, s[c], 0, 0, 0);
        }

        float p[4][4];
        if (allv) {
            #pragma unroll
            for (int c = 0; c < 4; c++)
                #pragma unroll
                for (int v = 0; v < 4; v++)
                    p[c][v] = __expf(s[c][v] * 0.125f);
        } else {
            #pragma unroll
            for (int c = 0; c < 4; c++)
                #pragma unroll
                for (int v = 0; v < 4; v++)
                    p[c][v] = mk[k0 + c * 16 + quad * 4 + v]
                                  ? __expf(s[c][v] * 0.125f) : 0.f;
        }
        #pragma unroll
        for (int c = 0; c < 4; c++)
            #pragma unroll
            for (int v = 0; v < 4; v++)
                rs += p[c][v];

        u32 A0 = cvtpk_bf16(p[0][0], p[0][1]), B0 = cvtpk_bf16(p[1][0], p[1][1]);
        u32 A1 = cvtpk_bf16(p[0][2], p[0][3]), B1 = cvtpk_bf16(p[1][2], p[1][3]);
        u32 A2 = cvtpk_bf16(p[2][0], p[2][1]), B2 = cvtpk_bf16(p[3][0], p[3][1]);
        u32 A3 = cvtpk_bf16(p[2][2], p[2][3]), B3 = cvtpk_bf16(p[3][2], p[3][3]);
        quad_gather(A0, B0);
        quad_gather(A1, B1);
        quad_gather(A2, B2);
        quad_gather(A3, B3);
        union { u32 w[4]; bf16x8 v; } pa0, pa1;
        pa0.w[0] = A0; pa0.w[1] = A1; pa0.w[2] = B0; pa0.w[3] = B1;
        pa1.w[0] = A2; pa1.w[1] = A3; pa1.w[2] = B2; pa1.w[3] = B3;

        #pragma unroll
        for (int nb = 0; nb < 4; nb++) {
            const u16* vb = &Vs[(nb * 16 + l16) * 64];
            const bf16x8 vf0 = *(const bf16x8*)&vb[rg0];
            const bf16x8 vf1 = *(const bf16x8*)&vb[rg1];
            o[nb] = __builtin_amdgcn_mfma_f32_16x16x32_bf16(pa0.v, vf0, o[nb], 0, 0, 0);
            o[nb] = __builtin_amdgcn_mfma_f32_16x16x32_bf16(pa1.v, vf1, o[nb], 0, 0, 0);
        }
    }

    rs += __shfl_xor(rs, 16, 64);
    rs += __shfl_xor(rs, 32, 64);
    float inv[4];
    #pragma unroll
    for (int v = 0; v < 4; v++)
        inv[v] = 1.0f / __shfl(rs, quad * 4 + v, 64);

    #pragma unroll
    for (int nb = 0; nb < 4; nb++)
        #pragma unroll
        for (int v = 0; v < 4; v++) {
            const int t = qbase + quad * 4 + v;
            Xa[((size_t)b * TT + t) * DD + h * DKK + nb * 16 + l16] =
                f2bf(o[nb][v] * inv[v]);
        }
}

extern "C" void kernel_launch(void* const* d_in, const int* in_sizes, int n_in,
                              void* d_out, int out_size, void* d_ws, size_t ws_size,
                              hipStream_t stream) {
    const float* q    = (const float*)d_in[0];
    const float* k    = (const float*)d_in[1];
    const float* v    = (const float*)d_in[2];
    const int*   mask = (const int*)d_in[3];
    const float* Wq   = (const float*)d_in[4];
    const float* bq   = (const float*)d_in[5];
    const float* Wk   = (const float*)d_in[6];
    const float* bk   = (const float*)d_in[7];
    const float* Wv   = (const float*)d_in[8];
    const float* bv   = (const float*)d_in[9];
    const float* Wo   = (const float*)d_in[10];
    const float* bo   = (const float*)d_in[11];

    // ws layout (u16 elems): Qc|Kc|Vc (4M each) | Wqc|Wkc|Wvc|Woc (1M each)
    //                        | Qp|Kp|Vpt|Xa (4M each)
    u16* Qc  = (u16*)d_ws;
    u16* Kc  = Qc + (size_t)ACT;
    u16* Vc  = Kc + (size_t)ACT;
    u16* Wqc = Vc + (size_t)ACT;
    u16* Wkc = Wqc + (size_t)WTE;
    u16* Wvc = Wkc + (size_t)WTE;
    u16* Woc = Wvc + (size_t)WTE;
    u16* Qp  = Woc + (size_t)WTE;
    u16* Kp  = Qp + (size_t)ACT;
    u16* Vpt = Kp + (size_t)ACT;
    u16* Xa  = Vpt + (size_t)ACT;

    CvtArgs ca;
    ca.src[0] = q;  ca.dst[0] = Qc;
    ca.src[1] = k;  ca.dst[1] = Kc;
    ca.src[2] = v;  ca.dst[2] = Vc;
    ca.src[3] = Wq; ca.dst[3] = Wqc;
    ca.src[4] = Wk; ca.dst[4] = Wkc;
    ca.src[5] = Wv; ca.dst[5] = Wvc;
    ca.src[6] = Wo; ca.dst[6] = Woc;
    convert_bf16<<<1024, 256, 0, stream>>>(ca);

    qkv_gemm<<<dim3(768), 256, 0, stream>>>(
        Qc, Kc, Vc, Wqc, Wkc, Wvc, bq, bk, bv, Qp);

    attn_kernel<<<dim3(BB * HH * (TT / 128)), 512, 0, stream>>>(Qp, Kp, Vpt, mask, Xa);

    out_gemm<<<dim3(512), 256, 0, stream>>>(Xa, Woc, bo, (float*)d_out);
}

// Round 13
// 230.188 us; speedup vs baseline: 1.0174x; 1.0174x over previous
//
#include <hip/hip_runtime.h>

typedef unsigned short u16;
typedef unsigned int u32;
typedef __bf16 bf16x8 __attribute__((ext_vector_type(8)));
typedef float floatx4 __attribute__((ext_vector_type(4)));

#define BB 2
#define TT 2048
#define DD 1024
#define HH 16
#define DKK 64
#define ACT (BB * TT * DD)      // 4194304 elements
#define WTE (DD * DD)           // 1048576 elements

__device__ inline u16 f2bf(float f) {
    union { float f; u32 u; } c; c.f = f;
    u32 r = (c.u + 0x7fffu + ((c.u >> 16) & 1u)) >> 16;
    return (u16)r;
}
__device__ inline u32 pack2bf(float a, float b) {
    return (u32)f2bf(a) | ((u32)f2bf(b) << 16);
}

// async global->LDS, 16B per lane; LDS dest = wave-uniform base + lane*16
typedef __attribute__((address_space(1))) const u32 gas_u32;
typedef __attribute__((address_space(3))) u32 las_u32;
__device__ __forceinline__ void gl2lds16(const u16* g, u16* l) {
    __builtin_amdgcn_global_load_lds((gas_u32*)g, (las_u32*)l, 16, 0, 0);
}

// pack 2 f32 -> 1 u32 of 2 bf16 (RNE, bit-identical to f2bf), 1 VALU op
__device__ __forceinline__ u32 cvtpk_bf16(float lo, float hi) {
    u32 r;
    asm("v_cvt_pk_bf16_f32 %0, %1, %2" : "=v"(r) : "v"(lo), "v"(hi));
    return r;
}

// swap32 then swap16 between two VGPRs (quad = 16-lane group):
//   after: a = {a.q0, a.q2, b.q0, b.q2}, b = {a.q1, a.q3, b.q1, b.q3}
__device__ __forceinline__ void quad_gather(u32 &a, u32 &b) {
    asm volatile("s_nop 1\n\t"
                 "v_permlane32_swap_b32 %0, %1\n\t"
                 "s_nop 1\n\t"
                 "v_permlane16_swap_b32 %0, %1"
                 : "+v"(a), "+v"(b));
}

// ---------------- fp32 -> bf16 convert pass ----------------
// t=0..2: activations (256 blocks x 16384 floats); t=3..6: weights (64 blocks)
// (In-flight conversion inside qkv_gemm was tried R9/R10: latency-bound,
// 86-93us vs 56us here. gl2lds from pre-converted bf16 wins.)
struct CvtArgs { const float* src[7]; u16* dst[7]; };
__global__ __launch_bounds__(256) void convert_bf16(CvtArgs a) {
    int bid = blockIdx.x, t, local;
    if (bid < 768) { t = bid >> 8; local = bid & 255; }
    else { int r = bid - 768; t = 3 + (r >> 6); local = r & 63; }
    const float* s = a.src[t];
    u16* d = a.dst[t];
    const int base = local * 16384;
    for (int i = 0; i < 8; i++) {
        const int idx = base + i * 2048 + threadIdx.x * 8;
        float4 x0 = *(const float4*)(s + idx);
        float4 x1 = *(const float4*)(s + idx + 4);
        uint4 p;
        p.x = pack2bf(x0.x, x0.y); p.y = pack2bf(x0.z, x0.w);
        p.z = pack2bf(x1.x, x1.y); p.w = pack2bf(x1.z, x1.w);
        *(uint4*)(d + idx) = p;
    }
}

// ---------------- fused QKV projection (R8 structure, measured-good) ------
// all-bf16 A[4096,1024] x W[1024,1024]^T; 128x32 LDS tiles via gl2lds w=16.
// grid = 768 1-D, XCD-bijective swizzle (8 x 96): A-panels fetched once per
// XCD, 2MB W slice L2-resident. z=0:Q z=1:K -> ws[b][h][t][dk];
// z=2:V -> [b][h][dk][t] with 8B packed uint2 stores.
__global__ __launch_bounds__(256) void qkv_gemm(
    const u16* __restrict__ Qc, const u16* __restrict__ Kc,
    const u16* __restrict__ Vc,
    const u16* __restrict__ Wqc, const u16* __restrict__ Wkc,
    const u16* __restrict__ Wvc,
    const float* __restrict__ bq, const float* __restrict__ bk,
    const float* __restrict__ bv,
    u16* __restrict__ ws)
{
    __shared__ __align__(16) u16 As[128 * 32];
    __shared__ __align__(16) u16 Bs[128 * 32];
    const int l = (blockIdx.x & 7) * 96 + (blockIdx.x >> 3);
    const int z = l >> 8;              // 256 logical blocks per slice
    const int yy = (l & 255) >> 3;     // m-panel
    const int xx = l & 7;              // n-panel
    const u16* A = (z == 0) ? Qc : (z == 1) ? Kc : Vc;
    const u16* W = (z == 0) ? Wqc : (z == 1) ? Wkc : Wvc;
    const float* bias = (z == 0) ? bq : (z == 1) ? bk : bv;
    u16* out = ws + (size_t)z * (size_t)BB * HH * TT * DKK;

    const int tid  = threadIdx.x;
    const int wave = tid >> 6, lane = tid & 63;
    const int quad = lane >> 4, l16 = lane & 15;
    const int wm = wave & 1, wn = wave >> 1;
    const int m0 = yy * 128, n0 = xx * 128;
    const int K = DD;

    const int lrow = lane >> 2, lcol = (lane & 3) * 8;
    const u16* Ag0 = A + (size_t)(m0 + wave * 16 + lrow) * K + lcol;
    const u16* Ag1 = A + (size_t)(m0 + 64 + wave * 16 + lrow) * K + lcol;
    const u16* Wg0 = W + (size_t)(n0 + wave * 16 + lrow) * K + lcol;
    const u16* Wg1 = W + (size_t)(n0 + 64 + wave * 16 + lrow) * K + lcol;
    u16* AsD0 = &As[(wave * 16) * 32];
    u16* AsD1 = &As[(64 + wave * 16) * 32];
    u16* BsD0 = &Bs[(wave * 16) * 32];
    u16* BsD1 = &Bs[(64 + wave * 16) * 32];

    floatx4 acc[4][4];
    for (int i = 0; i < 4; i++)
        for (int j = 0; j < 4; j++)
            acc[i][j] = floatx4{0.f, 0.f, 0.f, 0.f};

    for (int k0 = 0; k0 < K; k0 += 32) {
        __syncthreads();
        gl2lds16(Ag0 + k0, AsD0);
        gl2lds16(Ag1 + k0, AsD1);
        gl2lds16(Wg0 + k0, BsD0);
        gl2lds16(Wg1 + k0, BsD1);
        __syncthreads();   // compiler emits vmcnt(0) drain before barrier

        bf16x8 af[4], bfr[4];
        for (int mi = 0; mi < 4; mi++)
            af[mi] = *(const bf16x8*)&As[(wm * 64 + mi * 16 + l16) * 32 + quad * 8];
        for (int ni = 0; ni < 4; ni++)
            bfr[ni] = *(const bf16x8*)&Bs[(wn * 64 + ni * 16 + l16) * 32 + quad * 8];
        for (int mi = 0; mi < 4; mi++)
            for (int ni = 0; ni < 4; ni++)
                acc[mi][ni] = __builtin_amdgcn_mfma_f32_16x16x32_bf16(
                    af[mi], bfr[ni], acc[mi][ni], 0, 0, 0);
    }

    for (int ni = 0; ni < 4; ni++) {
        const int n = n0 + wn * 64 + ni * 16 + l16;
        const float bv2 = bias[n];
        const int h = n >> 6, dk = n & 63;
        for (int mi = 0; mi < 4; mi++) {
            if (z == 2) {
                // 4 consecutive t -> one aligned 8B store into V^T
                const int m = m0 + wm * 64 + mi * 16 + quad * 4;
                const int b = m >> 11, t = m & 2047;
                uint2 pp;
                pp.x = pack2bf(acc[mi][ni][0] + bv2, acc[mi][ni][1] + bv2);
                pp.y = pack2bf(acc[mi][ni][2] + bv2, acc[mi][ni][3] + bv2);
                *(uint2*)&out[(((size_t)(b * HH + h)) * DKK + dk) * TT + t] = pp;
            } else {
                for (int vv = 0; vv < 4; vv++) {
                    const int m = m0 + wm * 64 + mi * 16 + quad * 4 + vv;
                    const int b = m >> 11, t = m & 2047;
                    out[(((size_t)(b * HH + h)) * TT + t) * DKK + dk] =
                        f2bf(acc[mi][ni][vv] + bv2);
                }
            }
        }
    }
}

// ---------------- output projection: 64x128 tiles ----------------
// grid = 512 (2 blocks/CU, 8 waves/CU), XCD-bijective swizzle (512 = 8 x 64).
__global__ __launch_bounds__(256) void out_gemm(
    const u16* __restrict__ Av, const u16* __restrict__ Wv,
    const float* __restrict__ bias, float* __restrict__ outv)
{
    __shared__ __align__(16) u16 As[64 * 32];
    __shared__ __align__(16) u16 Bs[128 * 32];
    const int l = (blockIdx.x & 7) * 64 + (blockIdx.x >> 3);
    const int yy = l >> 3, xx = l & 7;
    const int tid  = threadIdx.x;
    const int wave = tid >> 6, lane = tid & 63;
    const int quad = lane >> 4, l16 = lane & 15;
    const int wm = wave & 1, wn = wave >> 1;
    const int m0 = yy * 64, n0 = xx * 128;
    const int K = DD, N = DD;

    const int lrow = lane >> 2, lcol = (lane & 3) * 8;
    const u16* Ag0 = Av + (size_t)(m0 + wave * 16 + lrow) * K + lcol;  // 64 rows
    const u16* Wg0 = Wv + (size_t)(n0 + wave * 16 + lrow) * K + lcol;
    const u16* Wg1 = Wv + (size_t)(n0 + 64 + wave * 16 + lrow) * K + lcol;
    u16* AsD0 = &As[(wave * 16) * 32];
    u16* BsD0 = &Bs[(wave * 16) * 32];
    u16* BsD1 = &Bs[(64 + wave * 16) * 32];

    floatx4 acc[2][4];
    for (int i = 0; i < 2; i++)
        for (int j = 0; j < 4; j++)
            acc[i][j] = floatx4{0.f, 0.f, 0.f, 0.f};

    for (int k0 = 0; k0 < K; k0 += 32) {
        __syncthreads();
        gl2lds16(Ag0 + k0, AsD0);
        gl2lds16(Wg0 + k0, BsD0);
        gl2lds16(Wg1 + k0, BsD1);
        __syncthreads();

        bf16x8 af[2], bfr[4];
        for (int mi = 0; mi < 2; mi++)
            af[mi] = *(const bf16x8*)&As[(wm * 32 + mi * 16 + l16) * 32 + quad * 8];
        for (int ni = 0; ni < 4; ni++)
            bfr[ni] = *(const bf16x8*)&Bs[(wn * 64 + ni * 16 + l16) * 32 + quad * 8];
        for (int mi = 0; mi < 2; mi++)
            for (int ni = 0; ni < 4; ni++)
                acc[mi][ni] = __builtin_amdgcn_mfma_f32_16x16x32_bf16(
                    af[mi], bfr[ni], acc[mi][ni], 0, 0, 0);
    }

    for (int ni = 0; ni < 4; ni++) {
        const int n = n0 + wn * 64 + ni * 16 + l16;
        const float bv2 = bias[n];
        for (int mi = 0; mi < 2; mi++)
            for (int vv = 0; vv < 4; vv++) {
                const int m = m0 + wm * 32 + mi * 16 + quad * 4 + vv;
                outv[(size_t)m * N + n] = acc[mi][ni][vv] + bv2;
            }
    }
}

// ---------------- flash attention: 8 waves x 16 q-rows, swizzled LDS ------
// 16 waves/CU, reg-staged K/V, zero-conflict XOR LDS swizzle, in-register P.
// XCD swizzle v2 (balance-aware): R12's bh-grouping gave perfect L2 locality
// (FETCH 69.7->12.4MB) but put both of a CU's blocks in the SAME batch; b=0
// CUs carried 64 tiles vs 56 balanced (mask skips 8/32 tiles for b=1) ->
// 57->61.6us. v2: XCD x owns bh {2x, 2x+1, 16+2x, 16+2x+1} (2 full + 2
// light); bid and bid+256 (same CU) differ by sel+2 -> one b=0 + one b=1
// block per CU. Locality AND balance.
__global__ __launch_bounds__(512) void attn_kernel(
    const u16* __restrict__ Qp, const u16* __restrict__ Kp,
    const u16* __restrict__ Vpt, const int* __restrict__ mask,
    u16* __restrict__ Xa)
{
    __shared__ __align__(16) u16 Ks[64 * 64];     // [key][dk] swizzled
    __shared__ __align__(16) u16 Vs[64 * 64];     // [dk][key] swizzled
    const int tid  = threadIdx.x;
    const int wave = tid >> 6, lane = tid & 63;
    const int quad = lane >> 4, l16 = lane & 15;
    const int bid = blockIdx.x;
    const int xcd = bid & 7;
    const int c   = bid >> 3;            // [0,64) within-XCD chunk index
    const int qt  = c & 15;
    const int sel = c >> 4;              // 0..3
    const int bh  = ((sel >> 1) << 4) + xcd * 2 + (sel & 1);
    const int b = bh >> 4, h = bh & 15;
    const int qbase = qt * 128 + wave * 16;

    const u16* Qb = Qp + (size_t)bh * TT * DKK;
    const u16* Kb = Kp + (size_t)bh * TT * DKK;
    const u16* Vb = Vpt + (size_t)bh * DKK * TT;
    const int* mk = mask + b * TT;

    const int srow = tid >> 3, sg = tid & 7;
    const int sgs = sg ^ (srow & 7);
    const u16* Ksrc = Kb + (size_t)srow * DKK + sgs * 8;
    const u16* Vsrc = Vb + (size_t)srow * TT + sgs * 8;
    u16* KsD = &Ks[srow * 64 + sg * 8];
    u16* VsD = &Vs[srow * 64 + sg * 8];

    const int x7 = l16 & 7;
    const int rg0 = (quad ^ x7) * 8;
    const int rg1 = ((quad + 4) ^ x7) * 8;

    const bf16x8 qf0 = *(const bf16x8*)&Qb[(size_t)(qbase + l16) * DKK + quad * 8];
    const bf16x8 qf1 = *(const bf16x8*)&Qb[(size_t)(qbase + l16) * DKK + 32 + quad * 8];

    floatx4 o[4];
    for (int i = 0; i < 4; i++) o[i] = floatx4{0.f, 0.f, 0.f, 0.f};
    float rs = 0.f;

    uint4 kr = *(const uint4*)Ksrc;
    uint4 vr = *(const uint4*)Vsrc;

    for (int ti = 0; ti < TT / 64; ti++) {
        const int k0 = ti * 64;
        __syncthreads();
        *(uint4*)KsD = kr;
        *(uint4*)VsD = vr;
        __syncthreads();
        if (ti + 1 < TT / 64) {
            kr = *(const uint4*)(Ksrc + (size_t)(k0 + 64) * DKK);
            vr = *(const uint4*)(Vsrc + (k0 + 64));
        }

        const int mv0 = mk[k0 + l16];
        const int mv1 = mk[k0 + 16 + l16];
        const int mv2 = mk[k0 + 32 + l16];
        const int mv3 = mk[k0 + 48 + l16];
        if (!__any(mv0 | mv1 | mv2 | mv3)) continue;
        const bool allv = __all(mv0 && mv1 && mv2 && mv3);

        bf16x8 kf[4][2];
        #pragma unroll
        for (int c2 = 0; c2 < 4; c2++) {
            const u16* kb = &Ks[(c2 * 16 + l16) * 64];
            kf[c2][0] = *(const bf16x8*)&kb[rg0];
            kf[c2][1] = *(const bf16x8*)&kb[rg1];
        }

        floatx4 s[4];
        #pragma unroll
        for (int c2 = 0; c2 < 4; c2++) s[c2] = floatx4{0.f, 0.f, 0.f, 0.f};
        #pragma unroll
        for (int c2 = 0; c2 < 4; c2++) {
            s[c2] = __builtin_amdgcn_mfma_f32_16x16x32_bf16(kf[c2][0], qf0, s[c2], 0, 0, 0);
            s[c2] = __builtin_amdgcn_mfma_f32_16x16x32_bf16(kf[c2][1], qf1, s[c2], 0, 0, 0);
        }

        float p[4][4];
        if (allv) {
            #pragma unroll
            for (int c2 = 0; c2 < 4; c2++)
                #pragma unroll
                for (int v = 0; v < 4; v++)
                    p[c2][v] = __expf(s[c2][v] * 0.125f);
        } else {
            #pragma unroll
            for (int c2 = 0; c2 < 4; c2++)
                #pragma unroll
                for (int v = 0; v < 4; v++)
                    p[c2][v] = mk[k0 + c2 * 16 + quad * 4 + v]
                                  ? __expf(s[c2][v] * 0.125f) : 0.f;
        }
        #pragma unroll
        for (int c2 = 0; c2 < 4; c2++)
            #pragma unroll
            for (int v = 0; v < 4; v++)
                rs += p[c2][v];

        u32 A0 = cvtpk_bf16(p[0][0], p[0][1]), B0 = cvtpk_bf16(p[1][0], p[1][1]);
        u32 A1 = cvtpk_bf16(p[0][2], p[0][3]), B1 = cvtpk_bf16(p[1][2], p[1][3]);
        u32 A2 = cvtpk_bf16(p[2][0], p[2][1]), B2 = cvtpk_bf16(p[3][0], p[3][1]);
        u32 A3 = cvtpk_bf16(p[2][2], p[2][3]), B3 = cvtpk_bf16(p[3][2], p[3][3]);
        quad_gather(A0, B0);
        quad_gather(A1, B1);
        quad_gather(A2, B2);
        quad_gather(A3, B3);
        union { u32 w[4]; bf16x8 v; } pa0, pa1;
        pa0.w[0] = A0; pa0.w[1] = A1; pa0.w[2] = B0; pa0.w[3] = B1;
        pa1.w[0] = A2; pa1.w[1] = A3; pa1.w[2] = B2; pa1.w[3] = B3;

        #pragma unroll
        for (int nb = 0; nb < 4; nb++) {
            const u16* vb = &Vs[(nb * 16 + l16) * 64];
            const bf16x8 vf0 = *(const bf16x8*)&vb[rg0];
            const bf16x8 vf1 = *(const bf16x8*)&vb[rg1];
            o[nb] = __builtin_amdgcn_mfma_f32_16x16x32_bf16(pa0.v, vf0, o[nb], 0, 0, 0);
            o[nb] = __builtin_amdgcn_mfma_f32_16x16x32_bf16(pa1.v, vf1, o[nb], 0, 0, 0);
        }
    }

    rs += __shfl_xor(rs, 16, 64);
    rs += __shfl_xor(rs, 32, 64);
    float inv[4];
    #pragma unroll
    for (int v = 0; v < 4; v++)
        inv[v] = 1.0f / __shfl(rs, quad * 4 + v, 64);

    #pragma unroll
    for (int nb = 0; nb < 4; nb++)
        #pragma unroll
        for (int v = 0; v < 4; v++) {
            const int t = qbase + quad * 4 + v;
            Xa[((size_t)b * TT + t) * DD + h * DKK + nb * 16 + l16] =
                f2bf(o[nb][v] * inv[v]);
        }
}

extern "C" void kernel_launch(void* const* d_in, const int* in_sizes, int n_in,
                              void* d_out, int out_size, void* d_ws, size_t ws_size,
                              hipStream_t stream) {
    const float* q    = (const float*)d_in[0];
    const float* k    = (const float*)d_in[1];
    const float* v    = (const float*)d_in[2];
    const int*   mask = (const int*)d_in[3];
    const float* Wq   = (const float*)d_in[4];
    const float* bq   = (const float*)d_in[5];
    const float* Wk   = (const float*)d_in[6];
    const float* bk   = (const float*)d_in[7];
    const float* Wv   = (const float*)d_in[8];
    const float* bv   = (const float*)d_in[9];
    const float* Wo   = (const float*)d_in[10];
    const float* bo   = (const float*)d_in[11];

    // ws layout (u16 elems): Qc|Kc|Vc (4M each) | Wqc|Wkc|Wvc|Woc (1M each)
    //                        | Qp|Kp|Vpt|Xa (4M each)
    u16* Qc  = (u16*)d_ws;
    u16* Kc  = Qc + (size_t)ACT;
    u16* Vc  = Kc + (size_t)ACT;
    u16* Wqc = Vc + (size_t)ACT;
    u16* Wkc = Wqc + (size_t)WTE;
    u16* Wvc = Wkc + (size_t)WTE;
    u16* Woc = Wvc + (size_t)WTE;
    u16* Qp  = Woc + (size_t)WTE;
    u16* Kp  = Qp + (size_t)ACT;
    u16* Vpt = Kp + (size_t)ACT;
    u16* Xa  = Vpt + (size_t)ACT;

    CvtArgs ca;
    ca.src[0] = q;  ca.dst[0] = Qc;
    ca.src[1] = k;  ca.dst[1] = Kc;
    ca.src[2] = v;  ca.dst[2] = Vc;
    ca.src[3] = Wq; ca.dst[3] = Wqc;
    ca.src[4] = Wk; ca.dst[4] = Wkc;
    ca.src[5] = Wv; ca.dst[5] = Wvc;
    ca.src[6] = Wo; ca.dst[6] = Woc;
    convert_bf16<<<1024, 256, 0, stream>>>(ca);

    qkv_gemm<<<dim3(768), 256, 0, stream>>>(
        Qc, Kc, Vc, Wqc, Wkc, Wvc, bq, bk, bv, Qp);

    attn_kernel<<<dim3(BB * HH * (TT / 128)), 512, 0, stream>>>(Qp, Kp, Vpt, mask, Xa);

    out_gemm<<<dim3(512), 256, 0, stream>>>(Xa, Woc, bo, (float*)d_out);
}

// Round 14
// 227.027 us; speedup vs baseline: 1.0315x; 1.0139x over previous
//
#include <hip/hip_runtime.h>

typedef unsigned short u16;
typedef unsigned int u32;
typedef __bf16 bf16x8 __attribute__((ext_vector_type(8)));
typedef float floatx4 __attribute__((ext_vector_type(4)));

#define BB 2
#define TT 2048
#define DD 1024
#define HH 16
#define DKK 64
#define ACT (BB * TT * DD)      // 4194304 elements
#define WTE (DD * DD)           // 1048576 elements

__device__ inline u16 f2bf(float f) {
    union { float f; u32 u; } c; c.f = f;
    u32 r = (c.u + 0x7fffu + ((c.u >> 16) & 1u)) >> 16;
    return (u16)r;
}
__device__ inline u32 pack2bf(float a, float b) {
    return (u32)f2bf(a) | ((u32)f2bf(b) << 16);
}

// async global->LDS, 16B per lane; LDS dest = wave-uniform base + lane*16
typedef __attribute__((address_space(1))) const u32 gas_u32;
typedef __attribute__((address_space(3))) u32 las_u32;
__device__ __forceinline__ void gl2lds16(const u16* g, u16* l) {
    __builtin_amdgcn_global_load_lds((gas_u32*)g, (las_u32*)l, 16, 0, 0);
}

// pack 2 f32 -> 1 u32 of 2 bf16 (RNE, bit-identical to f2bf), 1 VALU op
__device__ __forceinline__ u32 cvtpk_bf16(float lo, float hi) {
    u32 r;
    asm("v_cvt_pk_bf16_f32 %0, %1, %2" : "=v"(r) : "v"(lo), "v"(hi));
    return r;
}

// swap32 then swap16 between two VGPRs (quad = 16-lane group):
//   after: a = {a.q0, a.q2, b.q0, b.q2}, b = {a.q1, a.q3, b.q1, b.q3}
__device__ __forceinline__ void quad_gather(u32 &a, u32 &b) {
    asm volatile("s_nop 1\n\t"
                 "v_permlane32_swap_b32 %0, %1\n\t"
                 "s_nop 1\n\t"
                 "v_permlane16_swap_b32 %0, %1"
                 : "+v"(a), "+v"(b));
}

// ---------------- fp32 -> bf16 convert pass ----------------
// t=0..2: activations (256 blocks x 16384 floats); t=3..6: weights (64 blocks)
// (In-flight conversion inside qkv_gemm was tried R9/R10: latency-bound,
// 86-93us vs 56us here. gl2lds from pre-converted bf16 wins.)
struct CvtArgs { const float* src[7]; u16* dst[7]; };
__global__ __launch_bounds__(256) void convert_bf16(CvtArgs a) {
    int bid = blockIdx.x, t, local;
    if (bid < 768) { t = bid >> 8; local = bid & 255; }
    else { int r = bid - 768; t = 3 + (r >> 6); local = r & 63; }
    const float* s = a.src[t];
    u16* d = a.dst[t];
    const int base = local * 16384;
    for (int i = 0; i < 8; i++) {
        const int idx = base + i * 2048 + threadIdx.x * 8;
        float4 x0 = *(const float4*)(s + idx);
        float4 x1 = *(const float4*)(s + idx + 4);
        uint4 p;
        p.x = pack2bf(x0.x, x0.y); p.y = pack2bf(x0.z, x0.w);
        p.z = pack2bf(x1.x, x1.y); p.w = pack2bf(x1.z, x1.w);
        *(uint4*)(d + idx) = p;
    }
}

// ---------------- fused QKV projection (R8 structure, measured-good) ------
// all-bf16 A[4096,1024] x W[1024,1024]^T; 128x32 LDS tiles via gl2lds w=16.
// grid = 768 1-D, XCD-bijective swizzle (8 x 96): A-panels fetched once per
// XCD, 2MB W slice L2-resident. z=0:Q z=1:K -> ws[b][h][t][dk];
// z=2:V -> [b][h][dk][t] with 8B packed uint2 stores.
__global__ __launch_bounds__(256) void qkv_gemm(
    const u16* __restrict__ Qc, const u16* __restrict__ Kc,
    const u16* __restrict__ Vc,
    const u16* __restrict__ Wqc, const u16* __restrict__ Wkc,
    const u16* __restrict__ Wvc,
    const float* __restrict__ bq, const float* __restrict__ bk,
    const float* __restrict__ bv,
    u16* __restrict__ ws)
{
    __shared__ __align__(16) u16 As[128 * 32];
    __shared__ __align__(16) u16 Bs[128 * 32];
    const int l = (blockIdx.x & 7) * 96 + (blockIdx.x >> 3);
    const int z = l >> 8;              // 256 logical blocks per slice
    const int yy = (l & 255) >> 3;     // m-panel
    const int xx = l & 7;              // n-panel
    const u16* A = (z == 0) ? Qc : (z == 1) ? Kc : Vc;
    const u16* W = (z == 0) ? Wqc : (z == 1) ? Wkc : Wvc;
    const float* bias = (z == 0) ? bq : (z == 1) ? bk : bv;
    u16* out = ws + (size_t)z * (size_t)BB * HH * TT * DKK;

    const int tid  = threadIdx.x;
    const int wave = tid >> 6, lane = tid & 63;
    const int quad = lane >> 4, l16 = lane & 15;
    const int wm = wave & 1, wn = wave >> 1;
    const int m0 = yy * 128, n0 = xx * 128;
    const int K = DD;

    const int lrow = lane >> 2, lcol = (lane & 3) * 8;
    const u16* Ag0 = A + (size_t)(m0 + wave * 16 + lrow) * K + lcol;
    const u16* Ag1 = A + (size_t)(m0 + 64 + wave * 16 + lrow) * K + lcol;
    const u16* Wg0 = W + (size_t)(n0 + wave * 16 + lrow) * K + lcol;
    const u16* Wg1 = W + (size_t)(n0 + 64 + wave * 16 + lrow) * K + lcol;
    u16* AsD0 = &As[(wave * 16) * 32];
    u16* AsD1 = &As[(64 + wave * 16) * 32];
    u16* BsD0 = &Bs[(wave * 16) * 32];
    u16* BsD1 = &Bs[(64 + wave * 16) * 32];

    floatx4 acc[4][4];
    for (int i = 0; i < 4; i++)
        for (int j = 0; j < 4; j++)
            acc[i][j] = floatx4{0.f, 0.f, 0.f, 0.f};

    for (int k0 = 0; k0 < K; k0 += 32) {
        __syncthreads();
        gl2lds16(Ag0 + k0, AsD0);
        gl2lds16(Ag1 + k0, AsD1);
        gl2lds16(Wg0 + k0, BsD0);
        gl2lds16(Wg1 + k0, BsD1);
        __syncthreads();   // compiler emits vmcnt(0) drain before barrier

        bf16x8 af[4], bfr[4];
        for (int mi = 0; mi < 4; mi++)
            af[mi] = *(const bf16x8*)&As[(wm * 64 + mi * 16 + l16) * 32 + quad * 8];
        for (int ni = 0; ni < 4; ni++)
            bfr[ni] = *(const bf16x8*)&Bs[(wn * 64 + ni * 16 + l16) * 32 + quad * 8];
        for (int mi = 0; mi < 4; mi++)
            for (int ni = 0; ni < 4; ni++)
                acc[mi][ni] = __builtin_amdgcn_mfma_f32_16x16x32_bf16(
                    af[mi], bfr[ni], acc[mi][ni], 0, 0, 0);
    }

    for (int ni = 0; ni < 4; ni++) {
        const int n = n0 + wn * 64 + ni * 16 + l16;
        const float bv2 = bias[n];
        const int h = n >> 6, dk = n & 63;
        for (int mi = 0; mi < 4; mi++) {
            if (z == 2) {
                // 4 consecutive t -> one aligned 8B store into V^T
                const int m = m0 + wm * 64 + mi * 16 + quad * 4;
                const int b = m >> 11, t = m & 2047;
                uint2 pp;
                pp.x = pack2bf(acc[mi][ni][0] + bv2, acc[mi][ni][1] + bv2);
                pp.y = pack2bf(acc[mi][ni][2] + bv2, acc[mi][ni][3] + bv2);
                *(uint2*)&out[(((size_t)(b * HH + h)) * DKK + dk) * TT + t] = pp;
            } else {
                for (int vv = 0; vv < 4; vv++) {
                    const int m = m0 + wm * 64 + mi * 16 + quad * 4 + vv;
                    const int b = m >> 11, t = m & 2047;
                    out[(((size_t)(b * HH + h)) * TT + t) * DKK + dk] =
                        f2bf(acc[mi][ni][vv] + bv2);
                }
            }
        }
    }
}

// ---------------- output projection: 64x128 tiles ----------------
// grid = 512 (2 blocks/CU, 8 waves/CU), XCD-bijective swizzle (512 = 8 x 64).
__global__ __launch_bounds__(256) void out_gemm(
    const u16* __restrict__ Av, const u16* __restrict__ Wv,
    const float* __restrict__ bias, float* __restrict__ outv)
{
    __shared__ __align__(16) u16 As[64 * 32];
    __shared__ __align__(16) u16 Bs[128 * 32];
    const int l = (blockIdx.x & 7) * 64 + (blockIdx.x >> 3);
    const int yy = l >> 3, xx = l & 7;
    const int tid  = threadIdx.x;
    const int wave = tid >> 6, lane = tid & 63;
    const int quad = lane >> 4, l16 = lane & 15;
    const int wm = wave & 1, wn = wave >> 1;
    const int m0 = yy * 64, n0 = xx * 128;
    const int K = DD, N = DD;

    const int lrow = lane >> 2, lcol = (lane & 3) * 8;
    const u16* Ag0 = Av + (size_t)(m0 + wave * 16 + lrow) * K + lcol;  // 64 rows
    const u16* Wg0 = Wv + (size_t)(n0 + wave * 16 + lrow) * K + lcol;
    const u16* Wg1 = Wv + (size_t)(n0 + 64 + wave * 16 + lrow) * K + lcol;
    u16* AsD0 = &As[(wave * 16) * 32];
    u16* BsD0 = &Bs[(wave * 16) * 32];
    u16* BsD1 = &Bs[(64 + wave * 16) * 32];

    floatx4 acc[2][4];
    for (int i = 0; i < 2; i++)
        for (int j = 0; j < 4; j++)
            acc[i][j] = floatx4{0.f, 0.f, 0.f, 0.f};

    for (int k0 = 0; k0 < K; k0 += 32) {
        __syncthreads();
        gl2lds16(Ag0 + k0, AsD0);
        gl2lds16(Wg0 + k0, BsD0);
        gl2lds16(Wg1 + k0, BsD1);
        __syncthreads();

        bf16x8 af[2], bfr[4];
        for (int mi = 0; mi < 2; mi++)
            af[mi] = *(const bf16x8*)&As[(wm * 32 + mi * 16 + l16) * 32 + quad * 8];
        for (int ni = 0; ni < 4; ni++)
            bfr[ni] = *(const bf16x8*)&Bs[(wn * 64 + ni * 16 + l16) * 32 + quad * 8];
        for (int mi = 0; mi < 2; mi++)
            for (int ni = 0; ni < 4; ni++)
                acc[mi][ni] = __builtin_amdgcn_mfma_f32_16x16x32_bf16(
                    af[mi], bfr[ni], acc[mi][ni], 0, 0, 0);
    }

    for (int ni = 0; ni < 4; ni++) {
        const int n = n0 + wn * 64 + ni * 16 + l16;
        const float bv2 = bias[n];
        for (int mi = 0; mi < 2; mi++)
            for (int vv = 0; vv < 4; vv++) {
                const int m = m0 + wm * 32 + mi * 16 + quad * 4 + vv;
                outv[(size_t)m * N + n] = acc[mi][ni][vv] + bv2;
            }
    }
}

// ---------------- flash attention: 8 waves x 16 q-rows, swizzled LDS ------
// 16 waves/CU, reg-staged K/V, zero-conflict XOR LDS swizzle, in-register P,
// balance-aware XCD swizzle (R13, locality+balance verified).
// NEW R14: (a) per-tile mask any/all bits precomputed ONCE per wave via
// ballot into two u32 masks -- replaces 4 per-lane global loads + 2 ballots
// per tile per wave with 2 bit-tests; (b) exp fold: exp(s*0.125) =
// v_exp_f32(s * 0.125*log2e) with the fold in fp32 per element (one mul
// instead of two; NOT the R2 bf16-Q-prescale which broke numerics).
__global__ __launch_bounds__(512) void attn_kernel(
    const u16* __restrict__ Qp, const u16* __restrict__ Kp,
    const u16* __restrict__ Vpt, const int* __restrict__ mask,
    u16* __restrict__ Xa)
{
    __shared__ __align__(16) u16 Ks[64 * 64];     // [key][dk] swizzled
    __shared__ __align__(16) u16 Vs[64 * 64];     // [dk][key] swizzled
    const int tid  = threadIdx.x;
    const int wave = tid >> 6, lane = tid & 63;
    const int quad = lane >> 4, l16 = lane & 15;
    const int bid = blockIdx.x;
    const int xcd = bid & 7;
    const int c   = bid >> 3;            // [0,64) within-XCD chunk index
    const int qt  = c & 15;
    const int sel = c >> 4;              // 0..3
    const int bh  = ((sel >> 1) << 4) + xcd * 2 + (sel & 1);
    const int b = bh >> 4, h = bh & 15;
    const int qbase = qt * 128 + wave * 16;

    const u16* Qb = Qp + (size_t)bh * TT * DKK;
    const u16* Kb = Kp + (size_t)bh * TT * DKK;
    const u16* Vb = Vpt + (size_t)bh * DKK * TT;
    const int* mk = mask + b * TT;

    const int srow = tid >> 3, sg = tid & 7;
    const int sgs = sg ^ (srow & 7);
    const u16* Ksrc = Kb + (size_t)srow * DKK + sgs * 8;
    const u16* Vsrc = Vb + (size_t)srow * TT + sgs * 8;
    u16* KsD = &Ks[srow * 64 + sg * 8];
    u16* VsD = &Vs[srow * 64 + sg * 8];

    const int x7 = l16 & 7;
    const int rg0 = (quad ^ x7) * 8;
    const int rg1 = ((quad + 4) ^ x7) * 8;

    const bf16x8 qf0 = *(const bf16x8*)&Qb[(size_t)(qbase + l16) * DKK + quad * 8];
    const bf16x8 qf1 = *(const bf16x8*)&Qb[(size_t)(qbase + l16) * DKK + 32 + quad * 8];

    // per-tile mask summary, computed once: bit ti of anym/allm = tile ti
    // has any / all valid keys (lane l probes key ti*64 + l).
    u32 anym = 0, allm = 0;
    for (int ti2 = 0; ti2 < TT / 64; ti2++) {
        const unsigned long long bal = __ballot(mk[ti2 * 64 + lane] != 0);
        anym |= (bal != 0ull ? 1u : 0u) << ti2;
        allm |= (~bal == 0ull ? 1u : 0u) << ti2;
    }

    floatx4 o[4];
    for (int i = 0; i < 4; i++) o[i] = floatx4{0.f, 0.f, 0.f, 0.f};
    float rs = 0.f;

    uint4 kr = *(const uint4*)Ksrc;
    uint4 vr = *(const uint4*)Vsrc;

    for (int ti = 0; ti < TT / 64; ti++) {
        const int k0 = ti * 64;
        __syncthreads();
        *(uint4*)KsD = kr;
        *(uint4*)VsD = vr;
        __syncthreads();
        if (ti + 1 < TT / 64) {
            kr = *(const uint4*)(Ksrc + (size_t)(k0 + 64) * DKK);
            vr = *(const uint4*)(Vsrc + (k0 + 64));
        }

        if (!((anym >> ti) & 1u)) continue;        // tile fully masked
        const bool allv = (allm >> ti) & 1u;

        bf16x8 kf[4][2];
        #pragma unroll
        for (int c2 = 0; c2 < 4; c2++) {
            const u16* kb = &Ks[(c2 * 16 + l16) * 64];
            kf[c2][0] = *(const bf16x8*)&kb[rg0];
            kf[c2][1] = *(const bf16x8*)&kb[rg1];
        }

        floatx4 s[4];
        #pragma unroll
        for (int c2 = 0; c2 < 4; c2++) s[c2] = floatx4{0.f, 0.f, 0.f, 0.f};
        #pragma unroll
        for (int c2 = 0; c2 < 4; c2++) {
            s[c2] = __builtin_amdgcn_mfma_f32_16x16x32_bf16(kf[c2][0], qf0, s[c2], 0, 0, 0);
            s[c2] = __builtin_amdgcn_mfma_f32_16x16x32_bf16(kf[c2][1], qf1, s[c2], 0, 0, 0);
        }

        // p = exp(s*0.125) = 2^(s * 0.125*log2(e)); fold done in fp32.
        const float EXPC = 0.18033688011112042f;
        float p[4][4];
        if (allv) {
            #pragma unroll
            for (int c2 = 0; c2 < 4; c2++)
                #pragma unroll
                for (int v = 0; v < 4; v++) {
                    float pe;
                    asm("v_exp_f32 %0, %1" : "=v"(pe) : "v"(s[c2][v] * EXPC));
                    p[c2][v] = pe;
                }
        } else {
            #pragma unroll
            for (int c2 = 0; c2 < 4; c2++)
                #pragma unroll
                for (int v = 0; v < 4; v++) {
                    float pe;
                    asm("v_exp_f32 %0, %1" : "=v"(pe) : "v"(s[c2][v] * EXPC));
                    p[c2][v] = mk[k0 + c2 * 16 + quad * 4 + v] ? pe : 0.f;
                }
        }
        #pragma unroll
        for (int c2 = 0; c2 < 4; c2++)
            #pragma unroll
            for (int v = 0; v < 4; v++)
                rs += p[c2][v];

        u32 A0 = cvtpk_bf16(p[0][0], p[0][1]), B0 = cvtpk_bf16(p[1][0], p[1][1]);
        u32 A1 = cvtpk_bf16(p[0][2], p[0][3]), B1 = cvtpk_bf16(p[1][2], p[1][3]);
        u32 A2 = cvtpk_bf16(p[2][0], p[2][1]), B2 = cvtpk_bf16(p[3][0], p[3][1]);
        u32 A3 = cvtpk_bf16(p[2][2], p[2][3]), B3 = cvtpk_bf16(p[3][2], p[3][3]);
        quad_gather(A0, B0);
        quad_gather(A1, B1);
        quad_gather(A2, B2);
        quad_gather(A3, B3);
        union { u32 w[4]; bf16x8 v; } pa0, pa1;
        pa0.w[0] = A0; pa0.w[1] = A1; pa0.w[2] = B0; pa0.w[3] = B1;
        pa1.w[0] = A2; pa1.w[1] = A3; pa1.w[2] = B2; pa1.w[3] = B3;

        #pragma unroll
        for (int nb = 0; nb < 4; nb++) {
            const u16* vb = &Vs[(nb * 16 + l16) * 64];
            const bf16x8 vf0 = *(const bf16x8*)&vb[rg0];
            const bf16x8 vf1 = *(const bf16x8*)&vb[rg1];
            o[nb] = __builtin_amdgcn_mfma_f32_16x16x32_bf16(pa0.v, vf0, o[nb], 0, 0, 0);
            o[nb] = __builtin_amdgcn_mfma_f32_16x16x32_bf16(pa1.v, vf1, o[nb], 0, 0, 0);
        }
    }

    rs += __shfl_xor(rs, 16, 64);
    rs += __shfl_xor(rs, 32, 64);
    float inv[4];
    #pragma unroll
    for (int v = 0; v < 4; v++)
        inv[v] = 1.0f / __shfl(rs, quad * 4 + v, 64);

    #pragma unroll
    for (int nb = 0; nb < 4; nb++)
        #pragma unroll
        for (int v = 0; v < 4; v++) {
            const int t = qbase + quad * 4 + v;
            Xa[((size_t)b * TT + t) * DD + h * DKK + nb * 16 + l16] =
                f2bf(o[nb][v] * inv[v]);
        }
}

extern "C" void kernel_launch(void* const* d_in, const int* in_sizes, int n_in,
                              void* d_out, int out_size, void* d_ws, size_t ws_size,
                              hipStream_t stream) {
    const float* q    = (const float*)d_in[0];
    const float* k    = (const float*)d_in[1];
    const float* v    = (const float*)d_in[2];
    const int*   mask = (const int*)d_in[3];
    const float* Wq   = (const float*)d_in[4];
    const float* bq   = (const float*)d_in[5];
    const float* Wk   = (const float*)d_in[6];
    const float* bk   = (const float*)d_in[7];
    const float* Wv   = (const float*)d_in[8];
    const float* bv   = (const float*)d_in[9];
    const float* Wo   = (const float*)d_in[10];
    const float* bo   = (const float*)d_in[11];

    // ws layout (u16 elems): Qc|Kc|Vc (4M each) | Wqc|Wkc|Wvc|Woc (1M each)
    //                        | Qp|Kp|Vpt|Xa (4M each)
    u16* Qc  = (u16*)d_ws;
    u16* Kc  = Qc + (size_t)ACT;
    u16* Vc  = Kc + (size_t)ACT;
    u16* Wqc = Vc + (size_t)ACT;
    u16* Wkc = Wqc + (size_t)WTE;
    u16* Wvc = Wkc + (size_t)WTE;
    u16* Woc = Wvc + (size_t)WTE;
    u16* Qp  = Woc + (size_t)WTE;
    u16* Kp  = Qp + (size_t)ACT;
    u16* Vpt = Kp + (size_t)ACT;
    u16* Xa  = Vpt + (size_t)ACT;

    CvtArgs ca;
    ca.src[0] = q;  ca.dst[0] = Qc;
    ca.src[1] = k;  ca.dst[1] = Kc;
    ca.src[2] = v;  ca.dst[2] = Vc;
    ca.src[3] = Wq; ca.dst[3] = Wqc;
    ca.src[4] = Wk; ca.dst[4] = Wkc;
    ca.src[5] = Wv; ca.dst[5] = Wvc;
    ca.src[6] = Wo; ca.dst[6] = Woc;
    convert_bf16<<<1024, 256, 0, stream>>>(ca);

    qkv_gemm<<<dim3(768), 256, 0, stream>>>(
        Qc, Kc, Vc, Wqc, Wkc, Wvc, bq, bk, bv, Qp);

    attn_kernel<<<dim3(BB * HH * (TT / 128)), 512, 0, stream>>>(Qp, Kp, Vpt, mask, Xa);

    out_gemm<<<dim3(512), 256, 0, stream>>>(Xa, Woc, bo, (float*)d_out);
}